// Round 14
// baseline (113.459 us; speedup 1.0000x reference)
//
#include <hip/hip_runtime.h>
#include <hip/hip_bf16.h>
#include <stdint.h>

// TarMAC ensemble attention, MI355X/gfx950.
// E=128 ensembles x NB=256 agents, DQ=DK=DV=256 (D=768), f32 in/out, bf16 MFMA compute.
//
// R14: ldsKV staging DELETED (m169 lesson: don't LDS-stage what L2-fits).
//     K-e + Vt-e = 262 KB, L2-resident and shared by the 4 same-e blocks on one
//     XCD (swizzle). MFMA operands now load directly Kb/Vt -> registers with
//     SGPR-base addressing; ALL 8 tile barriers + double-buffer machinery gone
//     (the 2-buffer pipeline capped overlap at one MFMA-burst per load-latency —
//     the ~66us plateau of R7/R10/R13). Waves run free after aud; 2 barriers
//     remain (pos, audL-before-softmax). aud/softmax/permlane/C-write = R10.
//
// Workspace (32 MiB): Vt @ 0 (16 MiB), Kb @ 16 MiB (32768x256 bf16).

#define EE   128
#define NBB  256
#define DDIM 768
#define NEGV (-1000000.0f)

typedef __attribute__((ext_vector_type(8))) short short8;   // 8 x bf16 (4 VGPRs)
typedef __attribute__((ext_vector_type(4))) float f32x4;    // MFMA accumulator

__device__ __forceinline__ unsigned short f2bf(float f){
  union { float f; unsigned u; } v; v.f = f;
  return (unsigned short)((v.u + 0x7FFFu + ((v.u >> 16) & 1u)) >> 16);  // RNE, finite inputs
}
// RNE cast the compiler fuses into v_cvt_pk_bf16_f32 (m240: don't hand-write asm)
__device__ __forceinline__ unsigned short cvt1(float f){
  __hip_bfloat16 h = __float2bfloat16(f);
  unsigned short u; __builtin_memcpy(&u, &h, 2); return u;
}
__device__ __forceinline__ unsigned pk2(float lo, float hi){
  return (unsigned)cvt1(lo) | ((unsigned)cvt1(hi) << 16);
}

// Row-swaps across the 4 16-lane groups (rows) of a wave.
__device__ __forceinline__ void swap32(unsigned &a, unsigned &b){
#if __has_builtin(__builtin_amdgcn_permlane32_swap)
  auto r = __builtin_amdgcn_permlane32_swap(a, b, false, false);
  a = r[0]; b = r[1];
#else
  const int up = threadIdx.x & 32;
  const unsigned ax = __shfl_xor(a, 32), bx = __shfl_xor(b, 32);
  const unsigned na = up ? bx : a, nb = up ? b : ax;
  a = na; b = nb;
#endif
}
__device__ __forceinline__ void swap16(unsigned &a, unsigned &b){
#if __has_builtin(__builtin_amdgcn_permlane16_swap)
  auto r = __builtin_amdgcn_permlane16_swap(a, b, false, false);
  a = r[0]; b = r[1];
#else
  const int odd = threadIdx.x & 16;
  const unsigned ax = __shfl_xor(a, 16), bx = __shfl_xor(b, 16);
  const unsigned na = odd ? bx : a, nb = odd ? b : ax;
  a = na; b = nb;
#endif
}

// ---------- kernel 1: prep (R10 form, unchanged) ----------
// blocks [0,2048): V + noise -> transposed Vt[e][d][k] bf16.
// blocks [2048,6144): K + noise -> Kb[n][d] bf16 rows (streaming convert).
__global__ void k_prep(const float* __restrict__ qkv, const float* __restrict__ noise,
                       unsigned short* __restrict__ Vt, unsigned short* __restrict__ Kb){
  __shared__ unsigned short tile[64 * 66];
  if(blockIdx.x < 2048){
    const int b = blockIdx.x;
    const int e = b >> 4, t4 = b & 15;
    const int k0 = (t4 >> 2) << 6, d0 = (t4 & 3) << 6;
    const int u = threadIdx.x & 15, r = threadIdx.x >> 4;
    #pragma unroll
    for(int i = 0; i < 4; ++i){
      const int kl = r + (i << 4);
      const size_t off = ((size_t)(e*NBB + k0 + kl)) * DDIM + 512 + d0 + (u << 2);
      f32x4 v  = *(const f32x4*)(qkv   + off);
      f32x4 nz = *(const f32x4*)(noise + off);
      const int base = kl * 66 + (u << 2);
      tile[base+0] = f2bf(v[0]+nz[0]); tile[base+1] = f2bf(v[1]+nz[1]);
      tile[base+2] = f2bf(v[2]+nz[2]); tile[base+3] = f2bf(v[3]+nz[3]);
    }
    __syncthreads();
    #pragma unroll
    for(int i = 0; i < 4; ++i){
      const int dl = r + (i << 4);
      unsigned short o0 = tile[(u*4+0)*66 + dl];
      unsigned short o1 = tile[(u*4+1)*66 + dl];
      unsigned short o2 = tile[(u*4+2)*66 + dl];
      unsigned short o3 = tile[(u*4+3)*66 + dl];
      *(ushort4*)(Vt + ((size_t)(e*NBB + d0 + dl)) * NBB + k0 + (u << 2)) =
          make_ushort4(o0, o1, o2, o3);
    }
  } else {
    const int b2 = blockIdx.x - 2048;                 // [0,4096)
    const int n  = b2*8 + (threadIdx.x >> 5);         // row [0,32768)
    const int col = (threadIdx.x & 31) * 8;           // 8 elems of 256
    const size_t off = (size_t)n * DDIM + 256 + col;
    f32x4 a0 = *(const f32x4*)(qkv + off),   a1 = *(const f32x4*)(qkv + off + 4);
    f32x4 n0 = *(const f32x4*)(noise + off), n1 = *(const f32x4*)(noise + off + 4);
    short8 o;
    o[0]=f2bf(a0[0]+n0[0]); o[1]=f2bf(a0[1]+n0[1]); o[2]=f2bf(a0[2]+n0[2]); o[3]=f2bf(a0[3]+n0[3]);
    o[4]=f2bf(a1[0]+n1[0]); o[5]=f2bf(a1[1]+n1[1]); o[6]=f2bf(a1[2]+n1[2]); o[7]=f2bf(a1[3]+n1[3]);
    *(short8*)(Kb + (size_t)n * 256 + col) = o;
  }
}

// ---------- kernel 2: fused attention, barrier-free K/V from L2 ----------
// Block = (e, q-quarter): 4 waves x 16 q-rows each. 16x16x32 bf16 MFMA, swapped
// QK^T (S^T = mfma(K,Q)) -> lane-local softmax + in-register P via permlane.
// LDS: only aud (2KB) + pos (2KB). No tile buffers, no tile barriers.
__launch_bounds__(256, 2)
__global__ void k_attn(const float* __restrict__ qkv, const float* __restrict__ sp,
                       const unsigned char* __restrict__ m8, const int* __restrict__ m32,
                       const float* __restrict__ pos,
                       const unsigned short* __restrict__ Vt,
                       const unsigned short* __restrict__ Kb,
                       float* __restrict__ out){
  __shared__ unsigned audL[512];               // 64 rows x 8 words
  __shared__ float posx[NBB], posy[NBB];

  // bid = x + 8*qq + 32*c ; e = 16x + c  -> the 4 q-quarters of an ensemble all
  // land on XCD x (bid%8) -> Kb-e/Vt-e (262KB) stay hot in that XCD's L2.
  const int bid = blockIdx.x;
  const int e   = ((bid & 7) << 4) + (bid >> 5);
  const int qq  = (bid >> 3) & 3;
  const int tid  = threadIdx.x;
  const int wave = tid >> 6;
  const int lane = tid & 63;
  const int g    = lane >> 4;
  const int u    = lane & 15;
  const int q0   = qq * 64 + wave * 16;        // first q-row of this wave
  const size_t ebase = (size_t)e * NBB;

  // ---- phase 0: positions ----
  {
    const float2 p = *(const float2*)(pos + (ebase + tid) * 2);
    posx[tid] = p.x; posy[tid] = p.y;
  }
  const unsigned probe = ((const unsigned*)m32)[tid & 63];
  const int isInt = !__any(probe > 1u);        // wave-uniform dtype probe
  __syncthreads();                             // pos ready

  // ---- phase 1: Q fragments from f32 global (scale + RNE cvt), in flight early --
  const float scale = fabsf(sp[0]) + 1.0f;
  short8 qf[8];
  {
    const float* qrow = qkv + (ebase + q0 + u) * DDIM;
    #pragma unroll
    for(int dk = 0; dk < 8; ++dk){
      f32x4 a = *(const f32x4*)(qrow + dk*32 + g*8);
      f32x4 b = *(const f32x4*)(qrow + dk*32 + g*8 + 4);
      short8 f;
      f[0]=cvt1(a[0]*scale); f[1]=cvt1(a[1]*scale); f[2]=cvt1(a[2]*scale); f[3]=cvt1(a[3]*scale);
      f[4]=cvt1(b[0]*scale); f[5]=cvt1(b[1]*scale); f[6]=cvt1(b[2]*scale); f[7]=cvt1(b[3]*scale);
      qf[dk] = f;
    }
  }

  // ---- phase 2: audible bits (R10 staggered, bank-conflict-free) ----
  #pragma unroll
  for(int h = 0; h < 2; ++h){
    const int w   = tid + h * 256;             // word index within block [0,512)
    const int row = w >> 3;                    // q-row within block [0,64)
    const int j   = w & 7;                     // which 32-key word
    const float qx = posx[qq*64 + row], qy = posy[qq*64 + row];
    const size_t mbase = (ebase + qq*64 + row) * NBB + j * 32;
    unsigned wd = 0u;
    if(isInt){
      #pragma unroll
      for(int ii = 0; ii < 8; ++ii){
        const int blk = (ii + j) & 7;          // stagger by word index
        const int4 mv = *(const int4*)(m32 + mbase + blk * 4);
        const int mvals[4] = {mv.x, mv.y, mv.z, mv.w};
        #pragma unroll
        for(int jj = 0; jj < 4; ++jj){
          const int kk = blk * 4 + jj;
          const int k  = j * 32 + kk;
          const float dx = posx[k] - qx, dy = posy[k] - qy;
          // block fp-contract so sqrt boundary matches numpy exactly
          const float d2 = __fadd_rn(__fmul_rn(dx, dx), __fmul_rn(dy, dy));
          if((mvals[jj] != 0) && (sqrtf(d2) < 15.0f)) wd |= 1u << kk;
        }
      }
    } else {
      #pragma unroll
      for(int i = 0; i < 2; ++i){
        const int4 mv = *(const int4*)(m8 + mbase + i * 16);   // 16 bool bytes
        const int mvals[4] = {mv.x, mv.y, mv.z, mv.w};
        #pragma unroll
        for(int jt = 0; jt < 4; ++jt){
          const int jj = (jt + j) & 3;         // stagger byte-groups -> 2-way (free)
          #pragma unroll
          for(int b = 0; b < 4; ++b){
            const int kk = i * 16 + jj * 4 + b;
            const int k  = j * 32 + kk;
            const float dx = posx[k] - qx, dy = posy[k] - qy;
            const float d2 = __fadd_rn(__fmul_rn(dx, dx), __fadd_rn(__fmul_rn(dy, dy), 0.0f));
            if((((unsigned)mvals[jj] >> (8 * b)) & 0xFFu) && (sqrtf(d2) < 15.0f)) wd |= 1u << kk;
          }
        }
      }
    }
    audL[w] = wd;
  }

  // ---- phase 3: S^T = K Q^T, operands straight from L2-resident Kb ----
  // acc[t] at lane (g,u): S[k = t*16 + g*4 + r][q = u]; t spans all 256 keys.
  const f32x4 zero4 = {0.f, 0.f, 0.f, 0.f};
  f32x4 acc[16];
  #pragma unroll
  for(int nt = 0; nt < 16; ++nt) acc[nt] = zero4;

  {
    const unsigned short* kbase = Kb + (ebase + u) * 256 + g*8;  // row u, frag col
    #pragma unroll
    for(int t = 0; t < 16; ++t){
      const unsigned short* kr = kbase + t * 16 * 256;           // rows t*16+u
      #pragma unroll
      for(int dk = 0; dk < 8; ++dk){
        short8 kb = *(const short8*)(kr + dk*32);
        acc[t] = __builtin_amdgcn_mfma_f32_16x16x32_bf16(kb, qf[dk], acc[t], 0, 0, 0);
      }
    }
  }

  __syncthreads();                             // audL (cross-wave rows) visible

  // ---- phase 4: mask + softmax, lane-local rows + 2 shfl reduces ----
  unsigned wmask[8];
  {
    const unsigned* arow = audL + (wave*16 + u) * 8;
    #pragma unroll
    for(int j = 0; j < 8; ++j) wmask[j] = arow[j];
  }
  const unsigned anyw = wmask[0]|wmask[1]|wmask[2]|wmask[3]|wmask[4]|wmask[5]|wmask[6]|wmask[7];
  const unsigned long long rowsAny = __ballot(anyw != 0u);   // bit u = row u has keys

  float m0=-3.0e38f, m1=-3.0e38f, m2=-3.0e38f, m3=-3.0e38f;
  #pragma unroll
  for(int nt = 0; nt < 16; ++nt){
    const unsigned wv = wmask[nt >> 1] >> (((nt & 1) << 4) + g*4);
    f32x4 s = acc[nt];
    s[0] = s[0]*0.0625f + ((wv      & 1u) ? 0.0f : NEGV);  // /sqrt(256) + mask bias
    s[1] = s[1]*0.0625f + (((wv>>1) & 1u) ? 0.0f : NEGV);
    s[2] = s[2]*0.0625f + (((wv>>2) & 1u) ? 0.0f : NEGV);
    s[3] = s[3]*0.0625f + (((wv>>3) & 1u) ? 0.0f : NEGV);
    acc[nt] = s;
    m0 = fmaxf(m0, s[0]); m1 = fmaxf(m1, s[1]);
    m2 = fmaxf(m2, s[2]); m3 = fmaxf(m3, s[3]);
  }
  float mx = fmaxf(fmaxf(m0, m1), fmaxf(m2, m3));
  mx = fmaxf(mx, __shfl_xor(mx, 16));
  mx = fmaxf(mx, __shfl_xor(mx, 32));
  float s0=0.f, s1=0.f, s2=0.f, s3=0.f;
  #pragma unroll
  for(int nt = 0; nt < 16; ++nt){
    f32x4 p = acc[nt];
    p[0] = __expf(p[0] - mx); p[1] = __expf(p[1] - mx);
    p[2] = __expf(p[2] - mx); p[3] = __expf(p[3] - mx);
    acc[nt] = p;
    s0 += p[0]; s1 += p[1]; s2 += p[2]; s3 += p[3];
  }
  float ssum = (s0 + s1) + (s2 + s3);
  ssum += __shfl_xor(ssum, 16);
  ssum += __shfl_xor(ssum, 32);
  const float inv = 1.0f / ssum;               // ssum >= 1 always (max element)

  // ---- phase 5: P -> bf16 in-register + permlane relayout to PV A-frags ----
  short8 pa[8];
  #pragma unroll
  for(int kt = 0; kt < 8; ++kt){
    unsigned cE = pk2(acc[2*kt][0]*inv,   acc[2*kt][1]*inv);
    unsigned dE = pk2(acc[2*kt][2]*inv,   acc[2*kt][3]*inv);
    unsigned cO = pk2(acc[2*kt+1][0]*inv, acc[2*kt+1][1]*inv);
    unsigned dO = pk2(acc[2*kt+1][2]*inv, acc[2*kt+1][3]*inv);
    swap32(cE, cO); swap16(cE, cO);
    swap32(dE, dO); swap16(dE, dO);
    union { short8 s; unsigned w[4]; } pk;
    pk.w[0] = cE; pk.w[1] = dE; pk.w[2] = cO; pk.w[3] = dO;
    pa[kt] = pk.s;
  }

  // ---- phase 6: x = P V, operands straight from L2-resident Vt ----
  #pragma unroll
  for(int dqt = 0; dqt < 4; ++dqt){
    f32x4 xacc[4];
    #pragma unroll
    for(int dt = 0; dt < 4; ++dt) xacc[dt] = zero4;
    #pragma unroll
    for(int dt = 0; dt < 4; ++dt){
      const unsigned short* vr = Vt + (ebase + dqt*64 + dt*16 + u) * 256 + g*8;
      #pragma unroll
      for(int kt = 0; kt < 8; ++kt){
        short8 bv = *(const short8*)(vr + kt*32);
        xacc[dt] = __builtin_amdgcn_mfma_f32_16x16x32_bf16(pa[kt], bv, xacc[dt], 0, 0, 0);
      }
    }
    #pragma unroll
    for(int r = 0; r < 4; ++r){
      const float zf = ((rowsAny >> (g*4 + r)) & 1ull) ? 1.0f : 0.0f;
      float* orow = out + (ebase + q0 + g*4 + r) * 256 + dqt*64;
      #pragma unroll
      for(int dt = 0; dt < 4; ++dt)
        orow[dt*16 + u] = xacc[dt][r] * zf;    // rows with no audible key -> 0
    }
  }
}

extern "C" void kernel_launch(void* const* d_in, const int* in_sizes, int n_in,
                              void* d_out, int out_size, void* d_ws, size_t ws_size,
                              hipStream_t stream){
  (void)in_sizes; (void)n_in; (void)out_size; (void)ws_size;  // needs 32 MB ws
  const float* qkv   = (const float*)d_in[0];
  const void*  mask  = d_in[1];
  const float* pos   = (const float*)d_in[2];
  const float* noise = (const float*)d_in[3];
  const float* sp    = (const float*)d_in[4];

  unsigned short* Vt = (unsigned short*)d_ws;
  unsigned short* Kb = (unsigned short*)((unsigned char*)d_ws + 16777216);
  float* outp = (float*)d_out;

  k_prep<<<6144, 256, 0, stream>>>(qkv, noise, Vt, Kb);
  k_attn<<<512, 256, 0, stream>>>(qkv, sp,
                                  (const unsigned char*)mask, (const int*)mask,
                                  pos, Vt, Kb, outp);
}

// Round 15
// 66.651 us; speedup vs baseline: 1.7023x; 1.7023x over previous
//
#include <hip/hip_runtime.h>
#include <hip/hip_bf16.h>
#include <stdint.h>

// TarMAC ensemble attention, MI355X/gfx950.
// E=128 ensembles x NB=256 agents, DQ=DK=DV=256 (D=768), f32 in/out, bf16 MFMA compute.
//
// R15 = R10 + T4 counted-vmcnt pipeline (the m97 barrier-drain fix).
// R10's loop exposed one full gload latency per tile: __syncthreads drains
// vmcnt(0) right after issuing the next tile. Now: 16 tiles x 32 rows, 3
// rotating 16KB buffers, depth-2 prefetch; per tile {s_waitcnt vmcnt(N);
// s_barrier; issue t+2; MFMA} with N counted (4 loads/wave/tile; +8 stores
// per PV iter). Tile t's loads are 2 iterations old at its wait -> ~free.
// Issue-after-barrier makes buffer reuse race-free (all waves passed
// MFMA(t-1) before its buffer is overwritten). Softmax between t=7/8 covers
// V-tiles 8,9 flight (T14). aud/softmax/permlane/C-write = R10 verbatim.
// (R14's no-LDS experiment reverted: per-wave re-reads cost 8x L2 traffic.)
//
// Workspace (32 MiB): Vt @ 0 (16 MiB), Kb @ 16 MiB (32768x256 bf16).

#define EE   128
#define NBB  256
#define DDIM 768
#define NEGV (-1000000.0f)

typedef __attribute__((ext_vector_type(8))) short short8;   // 8 x bf16 (4 VGPRs)
typedef __attribute__((ext_vector_type(4))) float f32x4;    // MFMA accumulator

__device__ __forceinline__ unsigned short f2bf(float f){
  union { float f; unsigned u; } v; v.f = f;
  return (unsigned short)((v.u + 0x7FFFu + ((v.u >> 16) & 1u)) >> 16);  // RNE, finite inputs
}
__device__ __forceinline__ unsigned short cvt1(float f){
  __hip_bfloat16 h = __float2bfloat16(f);
  unsigned short u; __builtin_memcpy(&u, &h, 2); return u;
}
__device__ __forceinline__ unsigned pk2(float lo, float hi){
  return (unsigned)cvt1(lo) | ((unsigned)cvt1(hi) << 16);
}

__device__ __forceinline__ void swap32(unsigned &a, unsigned &b){
#if __has_builtin(__builtin_amdgcn_permlane32_swap)
  auto r = __builtin_amdgcn_permlane32_swap(a, b, false, false);
  a = r[0]; b = r[1];
#else
  const int up = threadIdx.x & 32;
  const unsigned ax = __shfl_xor(a, 32), bx = __shfl_xor(b, 32);
  const unsigned na = up ? bx : a, nb = up ? b : ax;
  a = na; b = nb;
#endif
}
__device__ __forceinline__ void swap16(unsigned &a, unsigned &b){
#if __has_builtin(__builtin_amdgcn_permlane16_swap)
  auto r = __builtin_amdgcn_permlane16_swap(a, b, false, false);
  a = r[0]; b = r[1];
#else
  const int odd = threadIdx.x & 16;
  const unsigned ax = __shfl_xor(a, 16), bx = __shfl_xor(b, 16);
  const unsigned na = odd ? bx : a, nb = odd ? b : ax;
  a = na; b = nb;
#endif
}

// async global->LDS, 16B per lane; LDS dest = wave-uniform base + lane*16 (HW rule)
__device__ __forceinline__ void gload16(const void* g, void* l){
  __builtin_amdgcn_global_load_lds((const __attribute__((address_space(1))) unsigned*)g,
                                   (__attribute__((address_space(3))) unsigned*)l, 16, 0, 0);
}
// Stage a 32-row bf16 tile (this wave: rows wave*8..+8 = 4 gload16) with the
// read-side XOR swizzle folded into the per-lane GLOBAL column (m173).
__device__ __forceinline__ void gstage32(const unsigned short* __restrict__ base,
                                         unsigned short* __restrict__ buf,
                                         int wave, int lane){
  #pragma unroll
  for(int i = 0; i < 4; ++i){
    const int lrow = wave*8 + i*2 + (lane >> 5);
    const int col  = ((lane & 31) * 8) ^ ((lrow & 7) << 3);
    gload16(base + (size_t)lrow * 256 + col, buf + (wave*8 + i*2) * 256);
  }
}

// counted-vmcnt barrier: memory-clobbered asm pins ordering around s_barrier
#define WAITB(NSTR)                                                  \
  asm volatile("s_waitcnt vmcnt(" NSTR ")" ::: "memory");            \
  __builtin_amdgcn_s_barrier();                                      \
  asm volatile("" ::: "memory");

// ---------- kernel 1: prep (R10 form, unchanged) ----------
__global__ void k_prep(const float* __restrict__ qkv, const float* __restrict__ noise,
                       unsigned short* __restrict__ Vt, unsigned short* __restrict__ Kb){
  __shared__ unsigned short tile[64 * 66];
  if(blockIdx.x < 2048){
    const int b = blockIdx.x;
    const int e = b >> 4, t4 = b & 15;
    const int k0 = (t4 >> 2) << 6, d0 = (t4 & 3) << 6;
    const int u = threadIdx.x & 15, r = threadIdx.x >> 4;
    #pragma unroll
    for(int i = 0; i < 4; ++i){
      const int kl = r + (i << 4);
      const size_t off = ((size_t)(e*NBB + k0 + kl)) * DDIM + 512 + d0 + (u << 2);
      f32x4 v  = *(const f32x4*)(qkv   + off);
      f32x4 nz = *(const f32x4*)(noise + off);
      const int base = kl * 66 + (u << 2);
      tile[base+0] = f2bf(v[0]+nz[0]); tile[base+1] = f2bf(v[1]+nz[1]);
      tile[base+2] = f2bf(v[2]+nz[2]); tile[base+3] = f2bf(v[3]+nz[3]);
    }
    __syncthreads();
    #pragma unroll
    for(int i = 0; i < 4; ++i){
      const int dl = r + (i << 4);
      unsigned short o0 = tile[(u*4+0)*66 + dl];
      unsigned short o1 = tile[(u*4+1)*66 + dl];
      unsigned short o2 = tile[(u*4+2)*66 + dl];
      unsigned short o3 = tile[(u*4+3)*66 + dl];
      *(ushort4*)(Vt + ((size_t)(e*NBB + d0 + dl)) * NBB + k0 + (u << 2)) =
          make_ushort4(o0, o1, o2, o3);
    }
  } else {
    const int b2 = blockIdx.x - 2048;                 // [0,4096)
    const int n  = b2*8 + (threadIdx.x >> 5);         // row [0,32768)
    const int col = (threadIdx.x & 31) * 8;           // 8 elems of 256
    const size_t off = (size_t)n * DDIM + 256 + col;
    f32x4 a0 = *(const f32x4*)(qkv + off),   a1 = *(const f32x4*)(qkv + off + 4);
    f32x4 n0 = *(const f32x4*)(noise + off), n1 = *(const f32x4*)(noise + off + 4);
    short8 o;
    o[0]=f2bf(a0[0]+n0[0]); o[1]=f2bf(a0[1]+n0[1]); o[2]=f2bf(a0[2]+n0[2]); o[3]=f2bf(a0[3]+n0[3]);
    o[4]=f2bf(a1[0]+n1[0]); o[5]=f2bf(a1[1]+n1[1]); o[6]=f2bf(a1[2]+n1[2]); o[7]=f2bf(a1[3]+n1[3]);
    *(short8*)(Kb + (size_t)n * 256 + col) = o;
  }
}

// ---------- kernel 2: fused attention, counted-vmcnt 16-tile pipeline ----------
// Block = (e, q-quarter): 4 waves x 16 q-rows each. 16x16x32 bf16 MFMA, swapped
// QK^T (S^T = mfma(K,Q)) -> lane-local softmax + in-register P via permlane.
// LDS 53KB: 3 x 16KB tile buffers (rotating), aud 2KB, pos 2KB. 2 blocks/CU.
__launch_bounds__(256, 2)
__global__ void k_attn(const float* __restrict__ qkv, const float* __restrict__ sp,
                       const unsigned char* __restrict__ m8, const int* __restrict__ m32,
                       const float* __restrict__ pos,
                       const unsigned short* __restrict__ Vt,
                       const unsigned short* __restrict__ Kb,
                       float* __restrict__ out){
  extern __shared__ unsigned char smem[];
  unsigned short* const bufs[3] = {(unsigned short*)smem,
                                   (unsigned short*)(smem + 16384),
                                   (unsigned short*)(smem + 32768)};
  unsigned* audL = (unsigned*)(smem + 49152);               // 64 rows x 8 words
  float*    posx = (float*)(smem + 51200);                  // 256
  float*    posy = (float*)(smem + 52224);                  // 256

  // bid = x + 8*qq + 32*c ; e = 16x + c  -> 4 same-e quarters share one XCD's L2.
  const int bid = blockIdx.x;
  const int e   = ((bid & 7) << 4) + (bid >> 5);
  const int qq  = (bid >> 3) & 3;
  const int tid  = threadIdx.x;
  const int wave = tid >> 6;
  const int lane = tid & 63;
  const int g    = lane >> 4;
  const int u    = lane & 15;
  const int q0   = qq * 64 + wave * 16;        // first q-row of this wave
  const size_t ebase = (size_t)e * NBB;
  const unsigned short* Ke = Kb + ebase * 256;
  const unsigned short* Ve = Vt + ebase * 256;

  // ---- phase 0: positions; K tile0 issued under aud ----
  {
    const float2 p = *(const float2*)(pos + (ebase + tid) * 2);
    posx[tid] = p.x; posy[tid] = p.y;
  }
  const unsigned probe = ((const unsigned*)m32)[tid & 63];
  const int isInt = !__any(probe > 1u);        // wave-uniform dtype probe
  __syncthreads();                             // pos ready

  gstage32(Ke, bufs[0], wave, lane);           // tile 0 in flight

  // ---- phase 0b: audible bits (R10 staggered, bank-conflict-free) ----
  #pragma unroll
  for(int h = 0; h < 2; ++h){
    const int w   = tid + h * 256;             // word index within block [0,512)
    const int row = w >> 3;                    // q-row within block [0,64)
    const int j   = w & 7;                     // which 32-key word
    const float qx = posx[qq*64 + row], qy = posy[qq*64 + row];
    const size_t mbase = (ebase + qq*64 + row) * NBB + j * 32;
    unsigned wd = 0u;
    if(isInt){
      #pragma unroll
      for(int ii = 0; ii < 8; ++ii){
        const int blk = (ii + j) & 7;          // stagger by word index
        const int4 mv = *(const int4*)(m32 + mbase + blk * 4);
        const int mvals[4] = {mv.x, mv.y, mv.z, mv.w};
        #pragma unroll
        for(int jj = 0; jj < 4; ++jj){
          const int kk = blk * 4 + jj;
          const int k  = j * 32 + kk;
          const float dx = posx[k] - qx, dy = posy[k] - qy;
          // block fp-contract so sqrt boundary matches numpy exactly
          const float d2 = __fadd_rn(__fmul_rn(dx, dx), __fmul_rn(dy, dy));
          if((mvals[jj] != 0) && (sqrtf(d2) < 15.0f)) wd |= 1u << kk;
        }
      }
    } else {
      #pragma unroll
      for(int i = 0; i < 2; ++i){
        const int4 mv = *(const int4*)(m8 + mbase + i * 16);   // 16 bool bytes
        const int mvals[4] = {mv.x, mv.y, mv.z, mv.w};
        #pragma unroll
        for(int jt = 0; jt < 4; ++jt){
          const int jj = (jt + j) & 3;         // stagger byte-groups -> 2-way (free)
          #pragma unroll
          for(int b = 0; b < 4; ++b){
            const int kk = i * 16 + jj * 4 + b;
            const int k  = j * 32 + kk;
            const float dx = posx[k] - qx, dy = posy[k] - qy;
            const float d2 = __fadd_rn(__fmul_rn(dx, dx), __fmul_rn(dy, dy));
            if((((unsigned)mvals[jj] >> (8 * b)) & 0xFFu) && (sqrtf(d2) < 15.0f)) wd |= 1u << kk;
          }
        }
      }
    }
    audL[w] = wd;
  }

  gstage32(Ke + 32*256, bufs[1], wave, lane);  // tile 1 in flight

  // ---- phase 1: Q fragments from f32 global (scale + RNE cvt) ----
  const float scale = fabsf(sp[0]) + 1.0f;
  short8 qf[8];
  {
    const float* qrow = qkv + (ebase + q0 + u) * DDIM;
    #pragma unroll
    for(int dk = 0; dk < 8; ++dk){
      f32x4 a = *(const f32x4*)(qrow + dk*32 + g*8);
      f32x4 b = *(const f32x4*)(qrow + dk*32 + g*8 + 4);
      short8 f;
      f[0]=cvt1(a[0]*scale); f[1]=cvt1(a[1]*scale); f[2]=cvt1(a[2]*scale); f[3]=cvt1(a[3]*scale);
      f[4]=cvt1(b[0]*scale); f[5]=cvt1(b[1]*scale); f[6]=cvt1(b[2]*scale); f[7]=cvt1(b[3]*scale);
      qf[dk] = f;
    }
  }

  const f32x4 zero4 = {0.f, 0.f, 0.f, 0.f};
  f32x4 acc[16];
  #pragma unroll
  for(int nt = 0; nt < 16; ++nt) acc[nt] = zero4;

  __syncthreads();                             // tiles 0,1 landed; audL visible

  // ---- phase 2: QK^T over 8 K-tiles (32 rows each), depth-2 prefetch ----
  // per iteration: [wait vmcnt; barrier] [issue t+2] [16 MFMA on tile t].
  // vmcnt budget: 4 loads/wave/tile; tile t's loads are 2 iterations old.
  // acc[2t+nth] at lane (g,u): S[k = (2t+nth)*16 + g*4 + r][q = u]
  #pragma unroll
  for(int t = 0; t < 8; ++t){
    if(t > 0){ WAITB("4") }                    // tile t done; t+1's 4 may fly
    {           // issue tile t+2 (post-barrier: tile t-1's readers all done)
      const int tn = t + 2;
      const unsigned short* src = (tn < 8) ? (Ke + (size_t)tn * 32 * 256)
                                           : (Ve + (size_t)(tn - 8) * 32 * 256);
      gstage32(src, bufs[tn % 3], wave, lane);
    }
    const unsigned short* cur = bufs[t % 3];
    #pragma unroll
    for(int nth = 0; nth < 2; ++nth){
      const unsigned short* kr = cur + (nth*16 + u) * 256;
      const int sw = (u & 7) << 3;
      #pragma unroll
      for(int dk = 0; dk < 8; ++dk){
        short8 kb = *(const short8*)(kr + ((dk*32 + g*8) ^ sw));
        acc[t*2 + nth] = __builtin_amdgcn_mfma_f32_16x16x32_bf16(kb, qf[dk], acc[t*2 + nth], 0, 0, 0);
      }
    }
  }

  // ---- phase 3: mask + softmax (V-tiles 8,9 in flight underneath) ----
  unsigned wmask[8];
  {
    const unsigned* arow = audL + (wave*16 + u) * 8;
    #pragma unroll
    for(int j = 0; j < 8; ++j) wmask[j] = arow[j];
  }
  const unsigned anyw = wmask[0]|wmask[1]|wmask[2]|wmask[3]|wmask[4]|wmask[5]|wmask[6]|wmask[7];
  const unsigned long long rowsAny = __ballot(anyw != 0u);   // bit u = row u has keys

  float m0=-3.0e38f, m1=-3.0e38f, m2=-3.0e38f, m3=-3.0e38f;
  #pragma unroll
  for(int nt = 0; nt < 16; ++nt){
    const unsigned wv = wmask[nt >> 1] >> (((nt & 1) << 4) + g*4);
    f32x4 s = acc[nt];
    s[0] = s[0]*0.0625f + ((wv      & 1u) ? 0.0f : NEGV);  // /sqrt(256) + mask bias
    s[1] = s[1]*0.0625f + (((wv>>1) & 1u) ? 0.0f : NEGV);
    s[2] = s[2]*0.0625f + (((wv>>2) & 1u) ? 0.0f : NEGV);
    s[3] = s[3]*0.0625f + (((wv>>3) & 1u) ? 0.0f : NEGV);
    acc[nt] = s;
    m0 = fmaxf(m0, s[0]); m1 = fmaxf(m1, s[1]);
    m2 = fmaxf(m2, s[2]); m3 = fmaxf(m3, s[3]);
  }
  float mx = fmaxf(fmaxf(m0, m1), fmaxf(m2, m3));
  mx = fmaxf(mx, __shfl_xor(mx, 16));
  mx = fmaxf(mx, __shfl_xor(mx, 32));
  float s0=0.f, s1=0.f, s2=0.f, s3=0.f;
  #pragma unroll
  for(int nt = 0; nt < 16; ++nt){
    f32x4 p = acc[nt];
    p[0] = __expf(p[0] - mx); p[1] = __expf(p[1] - mx);
    p[2] = __expf(p[2] - mx); p[3] = __expf(p[3] - mx);
    acc[nt] = p;
    s0 += p[0]; s1 += p[1]; s2 += p[2]; s3 += p[3];
  }
  float ssum = (s0 + s1) + (s2 + s3);
  ssum += __shfl_xor(ssum, 16);
  ssum += __shfl_xor(ssum, 32);
  const float inv = 1.0f / ssum;               // ssum >= 1 always (max element)

  short8 pa[8];
  #pragma unroll
  for(int kt = 0; kt < 8; ++kt){
    unsigned cE = pk2(acc[2*kt][0]*inv,   acc[2*kt][1]*inv);
    unsigned dE = pk2(acc[2*kt][2]*inv,   acc[2*kt][3]*inv);
    unsigned cO = pk2(acc[2*kt+1][0]*inv, acc[2*kt+1][1]*inv);
    unsigned dO = pk2(acc[2*kt+1][2]*inv, acc[2*kt+1][3]*inv);
    swap32(cE, cO); swap16(cE, cO);
    swap32(dE, dO); swap16(dE, dO);
    union { short8 s; unsigned w[4]; } pk;
    pk.w[0] = cE; pk.w[1] = dE; pk.w[2] = cO; pk.w[3] = dO;
    pa[kt] = pk.s;
  }

  // ---- phase 4: PV over 8 V-tiles (32 d-rows each), same pipeline ----
  // vmcnt budget: newest ops at tile-t wait = tile t+1 loads (4) + prev-iter
  // stores (8) -> 12; first PV iter (t=8): no stores yet -> 4; t=15: only
  // iter-14 stores newer than tile 15's loads -> 8.
  #pragma unroll
  for(int t = 8; t < 16; ++t){
    if(t == 8)      { WAITB("4") }
    else if(t == 15){ WAITB("8") }
    else            { WAITB("12") }
    if(t + 2 < 16)
      gstage32(Ve + (size_t)(t - 6) * 32 * 256, bufs[(t + 2) % 3], wave, lane);
    const unsigned short* cur = bufs[t % 3];
    f32x4 xacc[2];
    xacc[0] = zero4; xacc[1] = zero4;
    #pragma unroll
    for(int dt = 0; dt < 2; ++dt){
      const unsigned short* vr = cur + (dt*16 + u) * 256;
      const int sw = (u & 7) << 3;
      #pragma unroll
      for(int kt = 0; kt < 8; ++kt){
        short8 bv = *(const short8*)(vr + ((kt*32 + g*8) ^ sw));
        xacc[dt] = __builtin_amdgcn_mfma_f32_16x16x32_bf16(pa[kt], bv, xacc[dt], 0, 0, 0);
      }
    }
    #pragma unroll
    for(int r = 0; r < 4; ++r){
      const float zf = ((rowsAny >> (g*4 + r)) & 1ull) ? 1.0f : 0.0f;
      float* orow = out + (ebase + q0 + g*4 + r) * 256 + (t - 8) * 32;
      orow[u]      = xacc[0][r] * zf;          // rows with no audible key -> 0
      orow[16 + u] = xacc[1][r] * zf;
    }
  }
}

extern "C" void kernel_launch(void* const* d_in, const int* in_sizes, int n_in,
                              void* d_out, int out_size, void* d_ws, size_t ws_size,
                              hipStream_t stream){
  (void)in_sizes; (void)n_in; (void)out_size; (void)ws_size;  // needs 32 MB ws
  const float* qkv   = (const float*)d_in[0];
  const void*  mask  = d_in[1];
  const float* pos   = (const float*)d_in[2];
  const float* noise = (const float*)d_in[3];
  const float* sp    = (const float*)d_in[4];

  unsigned short* Vt = (unsigned short*)d_ws;
  unsigned short* Kb = (unsigned short*)((unsigned char*)d_ws + 16777216);
  float* outp = (float*)d_out;

  k_prep<<<6144, 256, 0, stream>>>(qkv, noise, Vt, Kb);

  hipFuncSetAttribute((const void*)k_attn, hipFuncAttributeMaxDynamicSharedMemorySize, 54272);
  k_attn<<<512, 256, 54272, stream>>>(qkv, sp,
                                      (const unsigned char*)mask, (const int*)mask,
                                      pos, Vt, Kb, outp);
}